// Round 10
// baseline (380.325 us; speedup 1.0000x reference)
//
#include <hip/hip_runtime.h>

#define INV_SQRT2 0.70710678118654752440f
#define KH 0.35355339059327376220f   // INV_SQRT2 * 0.5 (output scale folded in)

// Stage-2 (first-stage) filter table as constexpr: compile-time indices after
// unroll -> coefficients fold to immediates; structural zeros kill 20% of FMAs.
constexpr float c_first[2][10][2] = {
  { { 0.00000000000000f,  0.00000000000000f},
    {-0.08838834764832f, -0.01122679215254f},
    { 0.08838834764832f,  0.01122679215254f},
    { 0.69587998903400f,  0.08838834764832f},
    { 0.69587998903400f,  0.08838834764832f},
    { 0.08838834764832f, -0.69587998903400f},
    {-0.08838834764832f,  0.69587998903400f},
    { 0.01122679215254f, -0.08838834764832f},
    { 0.01122679215254f, -0.08838834764832f},
    { 0.00000000000000f,  0.00000000000000f} },
  { { 0.01122679215254f,  0.00000000000000f},
    { 0.01122679215254f,  0.00000000000000f},
    {-0.08838834764832f, -0.08838834764832f},
    { 0.08838834764832f, -0.08838834764832f},
    { 0.69587998903400f,  0.69587998903400f},
    { 0.69587998903400f, -0.69587998903400f},
    { 0.08838834764832f,  0.08838834764832f},
    {-0.08838834764832f,  0.08838834764832f},
    { 0.00000000000000f,  0.01122679215254f},
    { 0.00000000000000f, -0.01122679215254f} }
};

// Stage-1 table stays __constant__: its [n]/[m] indices are runtime-uniform.
__constant__ float c_qshift[2][10][2] = {
  { { 0.03516384f,  0.00000000f},
    { 0.00000000f,  0.00000000f},
    {-0.08832942f, -0.11430184f},
    { 0.23389032f,  0.00000000f},
    { 0.76027237f,  0.58751830f},
    { 0.58751830f, -0.76027237f},
    { 0.00000000f,  0.23389032f},
    {-0.11430184f,  0.08832942f},
    { 0.00000000f,  0.00000000f},
    { 0.00000000f, -0.03516384f} },
  { { 0.00000000f, -0.03516384f},
    { 0.00000000f,  0.00000000f},
    {-0.11430184f,  0.08832942f},
    { 0.00000000f,  0.23389032f},
    { 0.58751830f, -0.76027237f},
    { 0.76027237f,  0.58751830f},
    { 0.23389032f,  0.00000000f},
    {-0.08832942f, -0.11430184f},
    { 0.00000000f,  0.00000000f},
    { 0.03516384f,  0.00000000f} }
};

// ---------------------------------------------------------------------------
// Stage 1: level-2 synthesis (Q-shift). Gather structure + pins.
// R10: SEG 16->8 (grid 3072 blocks -> 12 supplied/CU) + launch_bounds(128,4)
// (16 waves/CU = 50% vs 37.5%). Inputs are L3-resident (50 MB total) so the
// extra halo re-reads are L3 hits, not HBM traffic (unlike R2's regression,
// which paid 5x gather traffic with no LDS).
// ---------------------------------------------------------------------------
__global__ __launch_bounds__(128, 4) void idtcwt_stage1(
    const float* __restrict__ lows, const float* __restrict__ highs1,
    float* __restrict__ lo2)
{
  constexpr int HIN = 128, WIN = 128, C = 3, B = 16;
  constexpr int ROWF  = WIN * C;        // 384 floats per input row
  constexpr int ROWO  = 2 * WIN * C;    // 768 floats per output row
  constexpr int PLANE = HIN * WIN * C;  // 49152
  constexpr int SEG   = 8;

  const int jj = blockIdx.x * 128 + threadIdx.x;  // 0..383 = (t, c)
  const int c  = jj % 3;
  const int t  = jj / 3;                // input column 0..127
  const int z  = blockIdx.z;            // combo*16 + b
  const int combo = z >> 4;
  const int b     = z & 15;
  const int m = combo >> 1, n = combo & 1;

  const float* lo = lows + (combo * B + b) * PLANE;
  const int pa = (m == n) ? 0 : 1;
  const int pb = (m == n) ? 3 : 2;
  const float sgn = (m == 0) ? 1.0f : -1.0f;
  const int bandStride = B * PLANE;     // 786432
  const float* hA = highs1 + (pa * 3 * B + b) * PLANE;
  const float* hB = highs1 + (pb * 3 * B + b) * PLANE;

  int wc3[5];
#pragma unroll
  for (int p = 0; p < 5; ++p) {
    int w = t + 2 - p;
    if (w >= WIN) w -= WIN;
    if (w < 0)  w += WIN;
    wc3[p] = w * C + c;
  }

  float lae[5], lao[5], hae[5], hao[5];
#pragma unroll
  for (int k = 0; k < 5; ++k) { lae[k]=0.f; lao[k]=0.f; hae[k]=0.f; hao[k]=0.f; }

  const int s0 = blockIdx.y * SEG;
  float* outp = lo2 + (combo * B + b) * (4 * PLANE);

#pragma unroll 1
  for (int ui = 0; ui < SEG + 4; ++ui) {
    const int u  = (s0 - 2 + ui) & (HIN - 1);
#pragma unroll
    for (int k = 0; k < 4; ++k) { lae[k]=lae[k+1]; lao[k]=lao[k+1]; hae[k]=hae[k+1]; hao[k]=hao[k+1]; }
    const int rb = u * ROWF;

    float rl[5], rA[3][5], rB[3][5];
#pragma unroll
    for (int p = 0; p < 5; ++p) {
      const int idx = rb + wc3[p];
      rl[p]    = lo[idx];
      rA[0][p] = hA[idx];
      rB[0][p] = hB[idx];
      rA[1][p] = hA[idx +   bandStride];
      rB[1][p] = hB[idx +   bandStride];
      rA[2][p] = hA[idx + 2*bandStride];
      rB[2][p] = hB[idx + 2*bandStride];
    }
    // keep-alive pins: forbid chunking of the 35-load batch
    asm volatile("" :: "v"(rl[0]),"v"(rl[1]),"v"(rl[2]),"v"(rl[3]),"v"(rl[4]),
                       "v"(rA[0][0]),"v"(rA[0][1]),"v"(rA[0][2]),"v"(rA[0][3]),"v"(rA[0][4]),
                       "v"(rA[1][0]),"v"(rA[1][1]),"v"(rA[1][2]),"v"(rA[1][3]),"v"(rA[1][4]));
    asm volatile("" :: "v"(rA[2][0]),"v"(rA[2][1]),"v"(rA[2][2]),"v"(rA[2][3]),"v"(rA[2][4]),
                       "v"(rB[0][0]),"v"(rB[0][1]),"v"(rB[0][2]),"v"(rB[0][3]),"v"(rB[0][4]),
                       "v"(rB[1][0]),"v"(rB[1][1]),"v"(rB[1][2]),"v"(rB[1][3]),"v"(rB[1][4]));
    asm volatile("" :: "v"(rB[2][0]),"v"(rB[2][1]),"v"(rB[2][2]),"v"(rB[2][3]),"v"(rB[2][4]));

    float aLe=0.f, aLo=0.f, aHe=0.f, aHo=0.f;
#pragma unroll
    for (int p = 0; p < 5; ++p) {
      const float lv  = rl[p];
      const float lhv = (rA[0][p] + sgn * rB[0][p]) * INV_SQRT2;
      const float hlv = (rA[1][p] + sgn * rB[1][p]) * INV_SQRT2;
      const float hhv = (rA[2][p] + sgn * rB[2][p]) * INV_SQRT2;
      const float ce0 = c_qshift[n][9 - 2*p][0], ce1 = c_qshift[n][9 - 2*p][1];
      const float co0 = c_qshift[n][8 - 2*p][0], co1 = c_qshift[n][8 - 2*p][1];
      aLe += ce0 * lv  + ce1 * lhv;
      aLo += co0 * lv  + co1 * lhv;
      aHe += ce0 * hlv + ce1 * hhv;
      aHo += co0 * hlv + co1 * hhv;
    }
    lae[4]=aLe; lao[4]=aLo; hae[4]=aHe; hao[4]=aHo;

    if (ui >= 4) {
      const int s = s0 + ui - 4;
      float o00=0.f, o01=0.f, o10=0.f, o11=0.f;
#pragma unroll
      for (int p = 0; p < 5; ++p) {
        const float f0l = c_qshift[m][9 - 2*p][0], f0h = c_qshift[m][9 - 2*p][1];
        const float f1l = c_qshift[m][8 - 2*p][0], f1h = c_qshift[m][8 - 2*p][1];
        o00 += f0l*lae[4-p] + f0h*hae[4-p];
        o01 += f0l*lao[4-p] + f0h*hao[4-p];
        o10 += f1l*lae[4-p] + f1h*hae[4-p];
        o11 += f1l*lao[4-p] + f1h*hao[4-p];
      }
      float* q = outp + (2*s) * ROWO + (2*t) * C + c;
      q[0]        = o00;
      q[C]        = o01;
      q[ROWO]     = o10;
      q[ROWO + C] = o11;
    }
  }
}

// ---------------------------------------------------------------------------
// Stage 2: OCCUPANCY UNLOCK. R9 evidence: 3 waves/SIMD (grid AND 43.5KB-LDS
// capped) cannot cover ~700cy memory latency; all pipes idle 50-70%; three
// scheduling rounds (R7-R9) flat. R10:
//  - SINGLE-buffer LDS (21.76 KB) + split barriers per phase
//    (reads -> B1 -> overwrite -> B2): LDS cap 3 -> 7 blocks/CU.
//  - SEG 16->8: grid 1536 blocks -> 6 blocks/CU supplied -> 24 waves/CU (75%).
//  - launch_bounds(256,6): VGPR cap 85 (have ~76 incl. 6-deep window).
//  - circular window period 6 (NI=12=2x6), all indices static.
// Costs accepted: +20% compute & LDS traffic per output (12 iters/8 rows),
// FETCH +~20% (HBM at 30% has headroom).
// ---------------------------------------------------------------------------
__global__ __launch_bounds__(256, 6) void idtcwt_stage2(
    const float* __restrict__ lo2, const float* __restrict__ highs0,
    float* __restrict__ out)
{
  constexpr int HIN = 256, WIN = 256, C = 3, B = 16;
  constexpr int ROWF  = WIN * C;        // 768 floats per input row
  constexpr int ROWO  = 2 * WIN * C;    // 1536
  constexpr int PLANE = HIN * WIN * C;  // 196608
  constexpr int OPLANE = 512 * 512 * C; // 786432
  constexpr int SEG   = 8;
  constexpr int NI    = SEG + 4;        // 12 row phases
  constexpr int PITCH = 5;              // float4s per slot (16 arrays + pad)
  constexpr int BUFV4 = 272 * PITCH;    // 1360 float4 = 21,760 B

  __shared__ float4 lds4[BUFV4];        // SINGLE buffer -> 6+ blocks/CU

  const int tid = threadIdx.x;
  const int jj  = blockIdx.x * 256 + tid;  // 0..767 = (t,c)
  const int c   = jj % 3;
  const int t   = jj / 3;
  const int b   = blockIdx.z;

  const int bandStride = B * PLANE;
  const float* a0  = lo2 + (0 * B + b) * PLANE;           // l00
  const float* a1  = lo2 + (1 * B + b) * PLANE;           // l01
  const float* a2  = lo2 + (2 * B + b) * PLANE;           // l10
  const float* a3  = lo2 + (3 * B + b) * PLANE;           // l11
  const float* h00b0 = highs0 + (0 * 3 * B + b) * PLANE;
  const float* h01b0 = highs0 + (1 * 3 * B + b) * PLANE;
  const float* h10b0 = highs0 + (2 * 3 * B + b) * PLANE;
  const float* h11b0 = highs0 + (3 * 3 * B + b) * PLANE;
  const float* h00b1 = h00b0 + bandStride;
  const float* h01b1 = h01b0 + bandStride;
  const float* h10b1 = h10b0 + bandStride;
  const float* h11b1 = h11b0 + bandStride;
  const float* h00b2 = h00b0 + 2*bandStride;
  const float* h01b2 = h01b0 + 2*bandStride;
  const float* h10b2 = h10b0 + 2*bandStride;
  const float* h11b2 = h11b0 + 2*bandStride;

  // staging source offsets (slot k holds global jj' = 256*blockIdx.x - 6 + k)
  int j1 = jj - 6;   if (j1 < 0)     j1 += ROWF;   // slot tid
  int j2 = jj + 250; if (j2 >= ROWF) j2 -= ROWF;   // slot 256+tid (tid<12)
  const bool halo = (tid < 12);

  // circular window, period 6, all indices static after unroll
  float wla0e[6], wla0o[6], wla1e[6], wla1o[6];
  float wha0e[6], wha0o[6], wha1e[6], wha1o[6];
#pragma unroll
  for (int k = 0; k < 6; ++k) {
    wla0e[k]=0.f; wla0o[k]=0.f; wla1e[k]=0.f; wla1o[k]=0.f;
    wha0e[k]=0.f; wha0o[k]=0.f; wha1e[k]=0.f; wha1o[k]=0.f;
  }

  const int s0 = blockIdx.y * SEG;
  float* outb = out + b * OPLANE;

  float4 G0, G1, G2, G3;
  float4 Hh0 = make_float4(0.f,0.f,0.f,0.f), Hh1 = Hh0, Hh2 = Hh0, Hh3 = Hh0;

#define S2_LOAD(I)                                                           \
  {                                                                          \
    const int rb_ = ((s0 - 2 + (I)) & (HIN - 1)) * ROWF;                     \
    const int o1_ = rb_ + j1;                                                \
    G0 = make_float4(a0[o1_], a1[o1_], a2[o1_], a3[o1_]);                    \
    G1 = make_float4(h00b0[o1_], h11b0[o1_], h01b0[o1_], h10b0[o1_]);        \
    G2 = make_float4(h00b1[o1_], h11b1[o1_], h01b1[o1_], h10b1[o1_]);        \
    G3 = make_float4(h00b2[o1_], h11b2[o1_], h01b2[o1_], h10b2[o1_]);        \
    if (halo) {                                                              \
      const int o2_ = rb_ + j2;                                              \
      Hh0 = make_float4(a0[o2_], a1[o2_], a2[o2_], a3[o2_]);                 \
      Hh1 = make_float4(h00b0[o2_], h11b0[o2_], h01b0[o2_], h10b0[o2_]);     \
      Hh2 = make_float4(h00b1[o2_], h11b1[o2_], h01b1[o2_], h10b1[o2_]);     \
      Hh3 = make_float4(h00b2[o2_], h11b2[o2_], h01b2[o2_], h10b2[o2_]);     \
    }                                                                        \
  }

// pre-butterfly + 0.5-fold, then 4x ds_write_b128.
#define S2_WRITE()                                                           \
  {                                                                          \
    float4* w_ = lds4 + tid * PITCH;                                         \
    w_[0] = make_float4(G0.x*0.5f, G0.y*0.5f, G0.z*0.5f, G0.w*0.5f);         \
    w_[1] = make_float4((G1.x+G1.y)*KH, (G1.x-G1.y)*KH,                      \
                        (G1.z+G1.w)*KH, (G1.z-G1.w)*KH);                     \
    w_[2] = make_float4((G2.x+G2.y)*KH, (G2.x-G2.y)*KH,                      \
                        (G2.z+G2.w)*KH, (G2.z-G2.w)*KH);                     \
    w_[3] = make_float4((G3.x+G3.y)*KH, (G3.x-G3.y)*KH,                      \
                        (G3.z+G3.w)*KH, (G3.z-G3.w)*KH);                     \
    if (halo) {                                                              \
      float4* w2_ = lds4 + (256 + tid) * PITCH;                              \
      w2_[0] = make_float4(Hh0.x*0.5f, Hh0.y*0.5f, Hh0.z*0.5f, Hh0.w*0.5f);  \
      w2_[1] = make_float4((Hh1.x+Hh1.y)*KH, (Hh1.x-Hh1.y)*KH,               \
                           (Hh1.z+Hh1.w)*KH, (Hh1.z-Hh1.w)*KH);              \
      w2_[2] = make_float4((Hh2.x+Hh2.y)*KH, (Hh2.x-Hh2.y)*KH,               \
                           (Hh2.z+Hh2.w)*KH, (Hh2.z-Hh2.w)*KH);              \
      w2_[3] = make_float4((Hh3.x+Hh3.y)*KH, (Hh3.x-Hh3.y)*KH,               \
                           (Hh3.z+Hh3.w)*KH, (Hh3.z-Hh3.w)*KH);              \
    }                                                                        \
  }

  // ---- prologue: stage row 0 ----
  S2_LOAD(0);
  S2_WRITE();
  __syncthreads();

#pragma unroll 1
  for (int uo = 0; uo < 2; ++uo) {
#pragma unroll
    for (int k = 0; k < 6; ++k) {
      const int i = uo * 6 + k;           // window slot = k (static; i%6==k)

      if (i < NI - 1) {                   // k<5: always; k==5: uo==0 only
        S2_LOAD(i + 1);
        __builtin_amdgcn_sched_barrier(0);  // keep load issue at phase top
      }

      // ---- column pass from lds4: taps at slot tid + 12 - 3p ----
      float A0e=0.f,A0o=0.f,A1e=0.f,A1o=0.f, H0e=0.f,H0o=0.f,H1e=0.f,H1o=0.f;
#pragma unroll
      for (int p = 0; p < 5; ++p) {
        const float4* qp = lds4 + (tid + (12 - 3*p)) * PITCH;
        const float4 q0 = qp[0], q1 = qp[1], q2 = qp[2], q3 = qp[3];
        const float a0e = c_first[0][9-2*p][0], a0o = c_first[0][8-2*p][0];
        const float b0e = c_first[0][9-2*p][1], b0o = c_first[0][8-2*p][1];
        const float a1e = c_first[1][9-2*p][0], a1o = c_first[1][8-2*p][0];
        const float b1e = c_first[1][9-2*p][1], b1o = c_first[1][8-2*p][1];
        // lo2 terms (q0 = 0.5*(v00,v01,v10,v11))
        A0e += a0e*q0.x + a1e*q0.y;   A0o += a0o*q0.x + a1o*q0.y;
        A1e += a0e*q0.z + a1e*q0.w;   A1o += a0o*q0.z + a1o*q0.w;
        // LH band: q1 = (s1,d1,s2,d2)
        A0e += b0e*q1.x + b1e*q1.z;   A0o += b0o*q1.x + b1o*q1.z;
        A1e += b0e*q1.w + b1e*q1.y;   A1o += b0o*q1.w + b1o*q1.y;
        // HL band
        H0e += a0e*q2.x + a1e*q2.z;   H0o += a0o*q2.x + a1o*q2.z;
        H1e += a0e*q2.w + a1e*q2.y;   H1o += a0o*q2.w + a1o*q2.y;
        // HH band
        H0e += b0e*q3.x + b1e*q3.z;   H0o += b0o*q3.x + b1o*q3.z;
        H1e += b0e*q3.w + b1e*q3.y;   H1o += b0o*q3.w + b1o*q3.y;
      }
      wla0e[k]=A0e; wla0o[k]=A0o; wla1e[k]=A1e; wla1o[k]=A1o;
      wha0e[k]=H0e; wha0o[k]=H0o; wha1e[k]=H1e; wha1o[k]=H1o;

      if (i >= 4) {                       // k>=4: always; k<4: uo>=1
        const int s = s0 + i - 4;
        float o00=0.f, o01=0.f, o10=0.f, o11=0.f;
#pragma unroll
        for (int p = 0; p < 5; ++p) {
          const int kk = (k - p + 6) % 6;   // static
          const float f00 = c_first[0][9-2*p][0], g00 = c_first[0][9-2*p][1];
          const float f01 = c_first[0][8-2*p][0], g01 = c_first[0][8-2*p][1];
          const float f10 = c_first[1][9-2*p][0], g10 = c_first[1][9-2*p][1];
          const float f11 = c_first[1][8-2*p][0], g11 = c_first[1][8-2*p][1];
          o00 += f00*wla0e[kk] + g00*wha0e[kk] + f10*wla1e[kk] + g10*wha1e[kk];
          o01 += f00*wla0o[kk] + g00*wha0o[kk] + f10*wla1o[kk] + g10*wha1o[kk];
          o10 += f01*wla0e[kk] + g01*wha0e[kk] + f11*wla1e[kk] + g11*wha1e[kk];
          o11 += f01*wla0o[kk] + g01*wha0o[kk] + f11*wla1o[kk] + g11*wha1o[kk];
        }
        float* q = outb + (2*s) * ROWO + (2*t) * C + c;
        q[0]        = o00;   // 0.5 folded into staging
        q[C]        = o01;
        q[ROWO]     = o10;
        q[ROWO + C] = o11;
      }

      __syncthreads();                    // B1: all reads of lds4 complete
      if (i < NI - 1) {
        S2_WRITE();                       // overwrite with row i+1
      }
      __syncthreads();                    // B2: writes visible
    }
  }
#undef S2_LOAD
#undef S2_WRITE
}

extern "C" void kernel_launch(void* const* d_in, const int* in_sizes, int n_in,
                              void* d_out, int out_size, void* d_ws, size_t ws_size,
                              hipStream_t stream) {
  const float* highs0 = (const float*)d_in[0];  // (2,2,3,16,256,256,3)
  const float* highs1 = (const float*)d_in[1];  // (2,2,3,16,128,128,3)
  const float* lows   = (const float*)d_in[2];  // (2,2,16,128,128,3)
  float* out = (float*)d_out;                   // (16,512,512,3)
  float* lo2 = (float*)d_ws;                    // 50.3 MB

  // Stage 1: 16 row segments of 8; 4x16 planes
  dim3 b1(128), g1(3, 16, 64);
  hipLaunchKernelGGL(idtcwt_stage1, g1, b1, 0, stream, lows, highs1, lo2);

  // Stage 2: 32 row segments of 8; 16 batches -> 1536 blocks = 6/CU
  dim3 b2(256), g2(3, 32, 16);
  hipLaunchKernelGGL(idtcwt_stage2, g2, b2, 0, stream, lo2, highs0, out);
}

// Round 11
// 195.362 us; speedup vs baseline: 1.9468x; 1.9468x over previous
//
#include <hip/hip_runtime.h>

#define INV_SQRT2 0.70710678118654752440f
#define KH 0.35355339059327376220f   // INV_SQRT2 * 0.5 (output scale folded in)

// Stage-2 (first-stage) filter table as constexpr: compile-time indices after
// unroll -> coefficients fold to immediates; structural zeros kill 20% of FMAs.
constexpr float c_first[2][10][2] = {
  { { 0.00000000000000f,  0.00000000000000f},
    {-0.08838834764832f, -0.01122679215254f},
    { 0.08838834764832f,  0.01122679215254f},
    { 0.69587998903400f,  0.08838834764832f},
    { 0.69587998903400f,  0.08838834764832f},
    { 0.08838834764832f, -0.69587998903400f},
    {-0.08838834764832f,  0.69587998903400f},
    { 0.01122679215254f, -0.08838834764832f},
    { 0.01122679215254f, -0.08838834764832f},
    { 0.00000000000000f,  0.00000000000000f} },
  { { 0.01122679215254f,  0.00000000000000f},
    { 0.01122679215254f,  0.00000000000000f},
    {-0.08838834764832f, -0.08838834764832f},
    { 0.08838834764832f, -0.08838834764832f},
    { 0.69587998903400f,  0.69587998903400f},
    { 0.69587998903400f, -0.69587998903400f},
    { 0.08838834764832f,  0.08838834764832f},
    {-0.08838834764832f,  0.08838834764832f},
    { 0.00000000000000f,  0.01122679215254f},
    { 0.00000000000000f, -0.01122679215254f} }
};

// Stage-1 table stays __constant__: its [n]/[m] indices are runtime-uniform.
__constant__ float c_qshift[2][10][2] = {
  { { 0.03516384f,  0.00000000f},
    { 0.00000000f,  0.00000000f},
    {-0.08832942f, -0.11430184f},
    { 0.23389032f,  0.00000000f},
    { 0.76027237f,  0.58751830f},
    { 0.58751830f, -0.76027237f},
    { 0.00000000f,  0.23389032f},
    {-0.11430184f,  0.08832942f},
    { 0.00000000f,  0.00000000f},
    { 0.00000000f, -0.03516384f} },
  { { 0.00000000f, -0.03516384f},
    { 0.00000000f,  0.00000000f},
    {-0.11430184f,  0.08832942f},
    { 0.00000000f,  0.23389032f},
    { 0.58751830f, -0.76027237f},
    { 0.76027237f,  0.58751830f},
    { 0.23389032f,  0.00000000f},
    {-0.08832942f, -0.11430184f},
    { 0.00000000f,  0.00000000f},
    { 0.03516384f,  0.00000000f} }
};

// ---------------------------------------------------------------------------
// Stage 1: level-2 synthesis (Q-shift). Gather structure + pins, SEG=8,
// launch_bounds(128,4). (R10: equal to R9 within noise; kept.)
// ---------------------------------------------------------------------------
__global__ __launch_bounds__(128, 4) void idtcwt_stage1(
    const float* __restrict__ lows, const float* __restrict__ highs1,
    float* __restrict__ lo2)
{
  constexpr int HIN = 128, WIN = 128, C = 3, B = 16;
  constexpr int ROWF  = WIN * C;        // 384 floats per input row
  constexpr int ROWO  = 2 * WIN * C;    // 768 floats per output row
  constexpr int PLANE = HIN * WIN * C;  // 49152
  constexpr int SEG   = 8;

  const int jj = blockIdx.x * 128 + threadIdx.x;  // 0..383 = (t, c)
  const int c  = jj % 3;
  const int t  = jj / 3;                // input column 0..127
  const int z  = blockIdx.z;            // combo*16 + b
  const int combo = z >> 4;
  const int b     = z & 15;
  const int m = combo >> 1, n = combo & 1;

  const float* lo = lows + (combo * B + b) * PLANE;
  const int pa = (m == n) ? 0 : 1;
  const int pb = (m == n) ? 3 : 2;
  const float sgn = (m == 0) ? 1.0f : -1.0f;
  const int bandStride = B * PLANE;     // 786432
  const float* hA = highs1 + (pa * 3 * B + b) * PLANE;
  const float* hB = highs1 + (pb * 3 * B + b) * PLANE;

  int wc3[5];
#pragma unroll
  for (int p = 0; p < 5; ++p) {
    int w = t + 2 - p;
    if (w >= WIN) w -= WIN;
    if (w < 0)  w += WIN;
    wc3[p] = w * C + c;
  }

  float lae[5], lao[5], hae[5], hao[5];
#pragma unroll
  for (int k = 0; k < 5; ++k) { lae[k]=0.f; lao[k]=0.f; hae[k]=0.f; hao[k]=0.f; }

  const int s0 = blockIdx.y * SEG;
  float* outp = lo2 + (combo * B + b) * (4 * PLANE);

#pragma unroll 1
  for (int ui = 0; ui < SEG + 4; ++ui) {
    const int u  = (s0 - 2 + ui) & (HIN - 1);
#pragma unroll
    for (int k = 0; k < 4; ++k) { lae[k]=lae[k+1]; lao[k]=lao[k+1]; hae[k]=hae[k+1]; hao[k]=hao[k+1]; }
    const int rb = u * ROWF;

    float rl[5], rA[3][5], rB[3][5];
#pragma unroll
    for (int p = 0; p < 5; ++p) {
      const int idx = rb + wc3[p];
      rl[p]    = lo[idx];
      rA[0][p] = hA[idx];
      rB[0][p] = hB[idx];
      rA[1][p] = hA[idx +   bandStride];
      rB[1][p] = hB[idx +   bandStride];
      rA[2][p] = hA[idx + 2*bandStride];
      rB[2][p] = hB[idx + 2*bandStride];
    }
    // keep-alive pins: forbid chunking of the 35-load batch
    asm volatile("" :: "v"(rl[0]),"v"(rl[1]),"v"(rl[2]),"v"(rl[3]),"v"(rl[4]),
                       "v"(rA[0][0]),"v"(rA[0][1]),"v"(rA[0][2]),"v"(rA[0][3]),"v"(rA[0][4]),
                       "v"(rA[1][0]),"v"(rA[1][1]),"v"(rA[1][2]),"v"(rA[1][3]),"v"(rA[1][4]));
    asm volatile("" :: "v"(rA[2][0]),"v"(rA[2][1]),"v"(rA[2][2]),"v"(rA[2][3]),"v"(rA[2][4]),
                       "v"(rB[0][0]),"v"(rB[0][1]),"v"(rB[0][2]),"v"(rB[0][3]),"v"(rB[0][4]),
                       "v"(rB[1][0]),"v"(rB[1][1]),"v"(rB[1][2]),"v"(rB[1][3]),"v"(rB[1][4]));
    asm volatile("" :: "v"(rB[2][0]),"v"(rB[2][1]),"v"(rB[2][2]),"v"(rB[2][3]),"v"(rB[2][4]));

    float aLe=0.f, aLo=0.f, aHe=0.f, aHo=0.f;
#pragma unroll
    for (int p = 0; p < 5; ++p) {
      const float lv  = rl[p];
      const float lhv = (rA[0][p] + sgn * rB[0][p]) * INV_SQRT2;
      const float hlv = (rA[1][p] + sgn * rB[1][p]) * INV_SQRT2;
      const float hhv = (rA[2][p] + sgn * rB[2][p]) * INV_SQRT2;
      const float ce0 = c_qshift[n][9 - 2*p][0], ce1 = c_qshift[n][9 - 2*p][1];
      const float co0 = c_qshift[n][8 - 2*p][0], co1 = c_qshift[n][8 - 2*p][1];
      aLe += ce0 * lv  + ce1 * lhv;
      aLo += co0 * lv  + co1 * lhv;
      aHe += ce0 * hlv + ce1 * hhv;
      aHo += co0 * hlv + co1 * hhv;
    }
    lae[4]=aLe; lao[4]=aLo; hae[4]=aHe; hao[4]=aHo;

    if (ui >= 4) {
      const int s = s0 + ui - 4;
      float o00=0.f, o01=0.f, o10=0.f, o11=0.f;
#pragma unroll
      for (int p = 0; p < 5; ++p) {
        const float f0l = c_qshift[m][9 - 2*p][0], f0h = c_qshift[m][9 - 2*p][1];
        const float f1l = c_qshift[m][8 - 2*p][0], f1h = c_qshift[m][8 - 2*p][1];
        o00 += f0l*lae[4-p] + f0h*hae[4-p];
        o01 += f0l*lao[4-p] + f0h*hao[4-p];
        o10 += f1l*lae[4-p] + f1h*hae[4-p];
        o11 += f1l*lao[4-p] + f1h*hao[4-p];
      }
      float* q = outp + (2*s) * ROWO + (2*t) * C + c;
      q[0]        = o00;
      q[C]        = o01;
      q[ROWO]     = o10;
      q[ROWO + C] = o11;
    }
  }
}

// ---------------------------------------------------------------------------
// Stage 2: R10 structure (single-buffer 21.76KB LDS + SEG=8 -> occupancy
// unlock PROVEN: 68% achieved) with the spill fixed: launch_bounds(256,4)
// gives VGPR cap 128 >= the ~100 this kernel needs. R10's (256,6) cap of 85
// spilled the window to scratch (WRITE_SIZE 50->521MB, VGPR=40, b128 LDS ops
// scalarized -> 7.5M bank conflicts, 355us). VGPR is now the occupancy cap:
// 4 blocks/CU resident = 16 waves/CU (50%) vs R9's 12.
// ---------------------------------------------------------------------------
__global__ __launch_bounds__(256, 4) void idtcwt_stage2(
    const float* __restrict__ lo2, const float* __restrict__ highs0,
    float* __restrict__ out)
{
  constexpr int HIN = 256, WIN = 256, C = 3, B = 16;
  constexpr int ROWF  = WIN * C;        // 768 floats per input row
  constexpr int ROWO  = 2 * WIN * C;    // 1536
  constexpr int PLANE = HIN * WIN * C;  // 196608
  constexpr int OPLANE = 512 * 512 * C; // 786432
  constexpr int SEG   = 8;
  constexpr int NI    = SEG + 4;        // 12 row phases
  constexpr int PITCH = 5;              // float4s per slot (16 arrays + pad)
  constexpr int BUFV4 = 272 * PITCH;    // 1360 float4 = 21,760 B

  __shared__ float4 lds4[BUFV4];        // SINGLE buffer

  const int tid = threadIdx.x;
  const int jj  = blockIdx.x * 256 + tid;  // 0..767 = (t,c)
  const int c   = jj % 3;
  const int t   = jj / 3;
  const int b   = blockIdx.z;

  const int bandStride = B * PLANE;
  const float* a0  = lo2 + (0 * B + b) * PLANE;           // l00
  const float* a1  = lo2 + (1 * B + b) * PLANE;           // l01
  const float* a2  = lo2 + (2 * B + b) * PLANE;           // l10
  const float* a3  = lo2 + (3 * B + b) * PLANE;           // l11
  const float* h00b0 = highs0 + (0 * 3 * B + b) * PLANE;
  const float* h01b0 = highs0 + (1 * 3 * B + b) * PLANE;
  const float* h10b0 = highs0 + (2 * 3 * B + b) * PLANE;
  const float* h11b0 = highs0 + (3 * 3 * B + b) * PLANE;
  const float* h00b1 = h00b0 + bandStride;
  const float* h01b1 = h01b0 + bandStride;
  const float* h10b1 = h10b0 + bandStride;
  const float* h11b1 = h11b0 + bandStride;
  const float* h00b2 = h00b0 + 2*bandStride;
  const float* h01b2 = h01b0 + 2*bandStride;
  const float* h10b2 = h10b0 + 2*bandStride;
  const float* h11b2 = h11b0 + 2*bandStride;

  // staging source offsets (slot k holds global jj' = 256*blockIdx.x - 6 + k)
  int j1 = jj - 6;   if (j1 < 0)     j1 += ROWF;   // slot tid
  int j2 = jj + 250; if (j2 >= ROWF) j2 -= ROWF;   // slot 256+tid (tid<12)
  const bool halo = (tid < 12);

  // circular window, period 6, all indices static after unroll
  float wla0e[6], wla0o[6], wla1e[6], wla1o[6];
  float wha0e[6], wha0o[6], wha1e[6], wha1o[6];
#pragma unroll
  for (int k = 0; k < 6; ++k) {
    wla0e[k]=0.f; wla0o[k]=0.f; wla1e[k]=0.f; wla1o[k]=0.f;
    wha0e[k]=0.f; wha0o[k]=0.f; wha1e[k]=0.f; wha1o[k]=0.f;
  }

  const int s0 = blockIdx.y * SEG;
  float* outb = out + b * OPLANE;

  float4 G0, G1, G2, G3;
  float4 Hh0 = make_float4(0.f,0.f,0.f,0.f), Hh1 = Hh0, Hh2 = Hh0, Hh3 = Hh0;

#define S2_LOAD(I)                                                           \
  {                                                                          \
    const int rb_ = ((s0 - 2 + (I)) & (HIN - 1)) * ROWF;                     \
    const int o1_ = rb_ + j1;                                                \
    G0 = make_float4(a0[o1_], a1[o1_], a2[o1_], a3[o1_]);                    \
    G1 = make_float4(h00b0[o1_], h11b0[o1_], h01b0[o1_], h10b0[o1_]);        \
    G2 = make_float4(h00b1[o1_], h11b1[o1_], h01b1[o1_], h10b1[o1_]);        \
    G3 = make_float4(h00b2[o1_], h11b2[o1_], h01b2[o1_], h10b2[o1_]);        \
    if (halo) {                                                              \
      const int o2_ = rb_ + j2;                                              \
      Hh0 = make_float4(a0[o2_], a1[o2_], a2[o2_], a3[o2_]);                 \
      Hh1 = make_float4(h00b0[o2_], h11b0[o2_], h01b0[o2_], h10b0[o2_]);     \
      Hh2 = make_float4(h00b1[o2_], h11b1[o2_], h01b1[o2_], h10b1[o2_]);     \
      Hh3 = make_float4(h00b2[o2_], h11b2[o2_], h01b2[o2_], h10b2[o2_]);     \
    }                                                                        \
  }

// pre-butterfly + 0.5-fold, then 4x ds_write_b128.
#define S2_WRITE()                                                           \
  {                                                                          \
    float4* w_ = lds4 + tid * PITCH;                                         \
    w_[0] = make_float4(G0.x*0.5f, G0.y*0.5f, G0.z*0.5f, G0.w*0.5f);         \
    w_[1] = make_float4((G1.x+G1.y)*KH, (G1.x-G1.y)*KH,                      \
                        (G1.z+G1.w)*KH, (G1.z-G1.w)*KH);                     \
    w_[2] = make_float4((G2.x+G2.y)*KH, (G2.x-G2.y)*KH,                      \
                        (G2.z+G2.w)*KH, (G2.z-G2.w)*KH);                     \
    w_[3] = make_float4((G3.x+G3.y)*KH, (G3.x-G3.y)*KH,                      \
                        (G3.z+G3.w)*KH, (G3.z-G3.w)*KH);                     \
    if (halo) {                                                              \
      float4* w2_ = lds4 + (256 + tid) * PITCH;                              \
      w2_[0] = make_float4(Hh0.x*0.5f, Hh0.y*0.5f, Hh0.z*0.5f, Hh0.w*0.5f);  \
      w2_[1] = make_float4((Hh1.x+Hh1.y)*KH, (Hh1.x-Hh1.y)*KH,               \
                           (Hh1.z+Hh1.w)*KH, (Hh1.z-Hh1.w)*KH);              \
      w2_[2] = make_float4((Hh2.x+Hh2.y)*KH, (Hh2.x-Hh2.y)*KH,               \
                           (Hh2.z+Hh2.w)*KH, (Hh2.z-Hh2.w)*KH);              \
      w2_[3] = make_float4((Hh3.x+Hh3.y)*KH, (Hh3.x-Hh3.y)*KH,               \
                           (Hh3.z+Hh3.w)*KH, (Hh3.z-Hh3.w)*KH);              \
    }                                                                        \
  }

  // ---- prologue: stage row 0 ----
  S2_LOAD(0);
  S2_WRITE();
  __syncthreads();

#pragma unroll 1
  for (int uo = 0; uo < 2; ++uo) {
#pragma unroll
    for (int k = 0; k < 6; ++k) {
      const int i = uo * 6 + k;           // window slot = k (static; i%6==k)

      if (i < NI - 1) {                   // k<5: always; k==5: uo==0 only
        S2_LOAD(i + 1);
        __builtin_amdgcn_sched_barrier(0);  // keep load issue at phase top
      }

      // ---- column pass from lds4: taps at slot tid + 12 - 3p ----
      float A0e=0.f,A0o=0.f,A1e=0.f,A1o=0.f, H0e=0.f,H0o=0.f,H1e=0.f,H1o=0.f;
#pragma unroll
      for (int p = 0; p < 5; ++p) {
        const float4* qp = lds4 + (tid + (12 - 3*p)) * PITCH;
        const float4 q0 = qp[0], q1 = qp[1], q2 = qp[2], q3 = qp[3];
        const float a0e = c_first[0][9-2*p][0], a0o = c_first[0][8-2*p][0];
        const float b0e = c_first[0][9-2*p][1], b0o = c_first[0][8-2*p][1];
        const float a1e = c_first[1][9-2*p][0], a1o = c_first[1][8-2*p][0];
        const float b1e = c_first[1][9-2*p][1], b1o = c_first[1][8-2*p][1];
        // lo2 terms (q0 = 0.5*(v00,v01,v10,v11))
        A0e += a0e*q0.x + a1e*q0.y;   A0o += a0o*q0.x + a1o*q0.y;
        A1e += a0e*q0.z + a1e*q0.w;   A1o += a0o*q0.z + a1o*q0.w;
        // LH band: q1 = (s1,d1,s2,d2)
        A0e += b0e*q1.x + b1e*q1.z;   A0o += b0o*q1.x + b1o*q1.z;
        A1e += b0e*q1.w + b1e*q1.y;   A1o += b0o*q1.w + b1o*q1.y;
        // HL band
        H0e += a0e*q2.x + a1e*q2.z;   H0o += a0o*q2.x + a1o*q2.z;
        H1e += a0e*q2.w + a1e*q2.y;   H1o += a0o*q2.w + a1o*q2.y;
        // HH band
        H0e += b0e*q3.x + b1e*q3.z;   H0o += b0o*q3.x + b1o*q3.z;
        H1e += b0e*q3.w + b1e*q3.y;   H1o += b0o*q3.w + b1o*q3.y;
      }
      wla0e[k]=A0e; wla0o[k]=A0o; wla1e[k]=A1e; wla1o[k]=A1o;
      wha0e[k]=H0e; wha0o[k]=H0o; wha1e[k]=H1e; wha1o[k]=H1o;

      if (i >= 4) {                       // k>=4: always; k<4: uo>=1
        const int s = s0 + i - 4;
        float o00=0.f, o01=0.f, o10=0.f, o11=0.f;
#pragma unroll
        for (int p = 0; p < 5; ++p) {
          const int kk = (k - p + 6) % 6;   // static
          const float f00 = c_first[0][9-2*p][0], g00 = c_first[0][9-2*p][1];
          const float f01 = c_first[0][8-2*p][0], g01 = c_first[0][8-2*p][1];
          const float f10 = c_first[1][9-2*p][0], g10 = c_first[1][9-2*p][1];
          const float f11 = c_first[1][8-2*p][0], g11 = c_first[1][8-2*p][1];
          o00 += f00*wla0e[kk] + g00*wha0e[kk] + f10*wla1e[kk] + g10*wha1e[kk];
          o01 += f00*wla0o[kk] + g00*wha0o[kk] + f10*wla1o[kk] + g10*wha1o[kk];
          o10 += f01*wla0e[kk] + g01*wha0e[kk] + f11*wla1e[kk] + g11*wha1e[kk];
          o11 += f01*wla0o[kk] + g01*wha0o[kk] + f11*wla1o[kk] + g11*wha1o[kk];
        }
        float* q = outb + (2*s) * ROWO + (2*t) * C + c;
        q[0]        = o00;   // 0.5 folded into staging
        q[C]        = o01;
        q[ROWO]     = o10;
        q[ROWO + C] = o11;
      }

      __syncthreads();                    // B1: all reads of lds4 complete
      if (i < NI - 1) {
        S2_WRITE();                       // overwrite with row i+1
      }
      __syncthreads();                    // B2: writes visible
    }
  }
#undef S2_LOAD
#undef S2_WRITE
}

extern "C" void kernel_launch(void* const* d_in, const int* in_sizes, int n_in,
                              void* d_out, int out_size, void* d_ws, size_t ws_size,
                              hipStream_t stream) {
  const float* highs0 = (const float*)d_in[0];  // (2,2,3,16,256,256,3)
  const float* highs1 = (const float*)d_in[1];  // (2,2,3,16,128,128,3)
  const float* lows   = (const float*)d_in[2];  // (2,2,16,128,128,3)
  float* out = (float*)d_out;                   // (16,512,512,3)
  float* lo2 = (float*)d_ws;                    // 50.3 MB

  // Stage 1: 16 row segments of 8; 4x16 planes
  dim3 b1(128), g1(3, 16, 64);
  hipLaunchKernelGGL(idtcwt_stage1, g1, b1, 0, stream, lows, highs1, lo2);

  // Stage 2: 32 row segments of 8; 16 batches -> 1536 blocks = 6/CU supplied
  dim3 b2(256), g2(3, 32, 16);
  hipLaunchKernelGGL(idtcwt_stage2, g2, b2, 0, stream, lo2, highs0, out);
}

// Round 12
// 149.688 us; speedup vs baseline: 2.5408x; 1.3051x over previous
//
#include <hip/hip_runtime.h>

#define INV_SQRT2 0.70710678118654752440f
#define KH 0.35355339059327376220f   // INV_SQRT2 * 0.5 (output scale folded in)

// Stage-2 (first-stage) filter table as constexpr: compile-time indices after
// unroll -> coefficients fold to immediates; structural zeros kill 20% of FMAs.
constexpr float c_first[2][10][2] = {
  { { 0.00000000000000f,  0.00000000000000f},
    {-0.08838834764832f, -0.01122679215254f},
    { 0.08838834764832f,  0.01122679215254f},
    { 0.69587998903400f,  0.08838834764832f},
    { 0.69587998903400f,  0.08838834764832f},
    { 0.08838834764832f, -0.69587998903400f},
    {-0.08838834764832f,  0.69587998903400f},
    { 0.01122679215254f, -0.08838834764832f},
    { 0.01122679215254f, -0.08838834764832f},
    { 0.00000000000000f,  0.00000000000000f} },
  { { 0.01122679215254f,  0.00000000000000f},
    { 0.01122679215254f,  0.00000000000000f},
    {-0.08838834764832f, -0.08838834764832f},
    { 0.08838834764832f, -0.08838834764832f},
    { 0.69587998903400f,  0.69587998903400f},
    { 0.69587998903400f, -0.69587998903400f},
    { 0.08838834764832f,  0.08838834764832f},
    {-0.08838834764832f,  0.08838834764832f},
    { 0.00000000000000f,  0.01122679215254f},
    { 0.00000000000000f, -0.01122679215254f} }
};

// Stage-1 table stays __constant__: its [n]/[m] indices are runtime-uniform.
__constant__ float c_qshift[2][10][2] = {
  { { 0.03516384f,  0.00000000f},
    { 0.00000000f,  0.00000000f},
    {-0.08832942f, -0.11430184f},
    { 0.23389032f,  0.00000000f},
    { 0.76027237f,  0.58751830f},
    { 0.58751830f, -0.76027237f},
    { 0.00000000f,  0.23389032f},
    {-0.11430184f,  0.08832942f},
    { 0.00000000f,  0.00000000f},
    { 0.00000000f, -0.03516384f} },
  { { 0.00000000f, -0.03516384f},
    { 0.00000000f,  0.00000000f},
    {-0.11430184f,  0.08832942f},
    { 0.00000000f,  0.23389032f},
    { 0.58751830f, -0.76027237f},
    { 0.76027237f,  0.58751830f},
    { 0.23389032f,  0.00000000f},
    {-0.08832942f, -0.11430184f},
    { 0.00000000f,  0.00000000f},
    { 0.03516384f,  0.00000000f} }
};

// ---------------------------------------------------------------------------
// Stage 1: level-2 synthesis (Q-shift) — R9 exact form (proven ~23us):
// SEG=16, launch_bounds(128,3), gather + keep-alive pins.
// (R10/R11's SEG=8 variant regressed to ~30us; reverted.)
// ---------------------------------------------------------------------------
__global__ __launch_bounds__(128, 3) void idtcwt_stage1(
    const float* __restrict__ lows, const float* __restrict__ highs1,
    float* __restrict__ lo2)
{
  constexpr int HIN = 128, WIN = 128, C = 3, B = 16;
  constexpr int ROWF  = WIN * C;        // 384 floats per input row
  constexpr int ROWO  = 2 * WIN * C;    // 768 floats per output row
  constexpr int PLANE = HIN * WIN * C;  // 49152
  constexpr int SEG   = 16;

  const int jj = blockIdx.x * 128 + threadIdx.x;  // 0..383 = (t, c)
  const int c  = jj % 3;
  const int t  = jj / 3;                // input column 0..127
  const int z  = blockIdx.z;            // combo*16 + b
  const int combo = z >> 4;
  const int b     = z & 15;
  const int m = combo >> 1, n = combo & 1;

  const float* lo = lows + (combo * B + b) * PLANE;
  const int pa = (m == n) ? 0 : 1;
  const int pb = (m == n) ? 3 : 2;
  const float sgn = (m == 0) ? 1.0f : -1.0f;
  const int bandStride = B * PLANE;     // 786432
  const float* hA = highs1 + (pa * 3 * B + b) * PLANE;
  const float* hB = highs1 + (pb * 3 * B + b) * PLANE;

  int wc3[5];
#pragma unroll
  for (int p = 0; p < 5; ++p) {
    int w = t + 2 - p;
    if (w >= WIN) w -= WIN;
    if (w < 0)  w += WIN;
    wc3[p] = w * C + c;
  }

  float lae[5], lao[5], hae[5], hao[5];
#pragma unroll
  for (int k = 0; k < 5; ++k) { lae[k]=0.f; lao[k]=0.f; hae[k]=0.f; hao[k]=0.f; }

  const int s0 = blockIdx.y * SEG;
  float* outp = lo2 + (combo * B + b) * (4 * PLANE);

#pragma unroll 1
  for (int ui = 0; ui < SEG + 4; ++ui) {
    const int u  = (s0 - 2 + ui) & (HIN - 1);
#pragma unroll
    for (int k = 0; k < 4; ++k) { lae[k]=lae[k+1]; lao[k]=lao[k+1]; hae[k]=hae[k+1]; hao[k]=hao[k+1]; }
    const int rb = u * ROWF;

    float rl[5], rA[3][5], rB[3][5];
#pragma unroll
    for (int p = 0; p < 5; ++p) {
      const int idx = rb + wc3[p];
      rl[p]    = lo[idx];
      rA[0][p] = hA[idx];
      rB[0][p] = hB[idx];
      rA[1][p] = hA[idx +   bandStride];
      rB[1][p] = hB[idx +   bandStride];
      rA[2][p] = hA[idx + 2*bandStride];
      rB[2][p] = hB[idx + 2*bandStride];
    }
    // keep-alive pins: forbid chunking of the 35-load batch
    asm volatile("" :: "v"(rl[0]),"v"(rl[1]),"v"(rl[2]),"v"(rl[3]),"v"(rl[4]),
                       "v"(rA[0][0]),"v"(rA[0][1]),"v"(rA[0][2]),"v"(rA[0][3]),"v"(rA[0][4]),
                       "v"(rA[1][0]),"v"(rA[1][1]),"v"(rA[1][2]),"v"(rA[1][3]),"v"(rA[1][4]));
    asm volatile("" :: "v"(rA[2][0]),"v"(rA[2][1]),"v"(rA[2][2]),"v"(rA[2][3]),"v"(rA[2][4]),
                       "v"(rB[0][0]),"v"(rB[0][1]),"v"(rB[0][2]),"v"(rB[0][3]),"v"(rB[0][4]),
                       "v"(rB[1][0]),"v"(rB[1][1]),"v"(rB[1][2]),"v"(rB[1][3]),"v"(rB[1][4]));
    asm volatile("" :: "v"(rB[2][0]),"v"(rB[2][1]),"v"(rB[2][2]),"v"(rB[2][3]),"v"(rB[2][4]));

    float aLe=0.f, aLo=0.f, aHe=0.f, aHo=0.f;
#pragma unroll
    for (int p = 0; p < 5; ++p) {
      const float lv  = rl[p];
      const float lhv = (rA[0][p] + sgn * rB[0][p]) * INV_SQRT2;
      const float hlv = (rA[1][p] + sgn * rB[1][p]) * INV_SQRT2;
      const float hhv = (rA[2][p] + sgn * rB[2][p]) * INV_SQRT2;
      const float ce0 = c_qshift[n][9 - 2*p][0], ce1 = c_qshift[n][9 - 2*p][1];
      const float co0 = c_qshift[n][8 - 2*p][0], co1 = c_qshift[n][8 - 2*p][1];
      aLe += ce0 * lv  + ce1 * lhv;
      aLo += co0 * lv  + co1 * lhv;
      aHe += ce0 * hlv + ce1 * hhv;
      aHo += co0 * hlv + co1 * hhv;
    }
    lae[4]=aLe; lao[4]=aLo; hae[4]=aHe; hao[4]=aHo;

    if (ui >= 4) {
      const int s = s0 + ui - 4;
      float o00=0.f, o01=0.f, o10=0.f, o11=0.f;
#pragma unroll
      for (int p = 0; p < 5; ++p) {
        const float f0l = c_qshift[m][9 - 2*p][0], f0h = c_qshift[m][9 - 2*p][1];
        const float f1l = c_qshift[m][8 - 2*p][0], f1h = c_qshift[m][8 - 2*p][1];
        o00 += f0l*lae[4-p] + f0h*hae[4-p];
        o01 += f0l*lao[4-p] + f0h*hao[4-p];
        o10 += f1l*lae[4-p] + f1h*hae[4-p];
        o11 += f1l*lao[4-p] + f1h*hao[4-p];
      }
      float* q = outp + (2*s) * ROWO + (2*t) * C + c;
      q[0]        = o00;
      q[C]        = o01;
      q[ROWO]     = o10;
      q[ROWO + C] = o11;
    }
  }
}

// ---------------------------------------------------------------------------
// Stage 2: single-buffer SEG=8 structure (R11) with LDS PADDED to 36,864 B.
// R11 evidence: at 21.76KB LDS the register allocator targets the LDS-implied
// occupancy (7 blocks/CU -> budget 512/7 -> 64-granule) and SPILLS (VGPR=64,
// WRITE 161MB) even though launch_bounds(256,4) allows 128. Padding LDS so
// the LDS-implied limit is exactly 4 blocks/CU makes the allocator budget
// 128 VGPR -> the ~100-reg working set fits -> no spill, 16 waves/CU (50%).
// One-variable experiment vs R11.
// ---------------------------------------------------------------------------
__global__ __launch_bounds__(256, 4) void idtcwt_stage2(
    const float* __restrict__ lo2, const float* __restrict__ highs0,
    float* __restrict__ out)
{
  constexpr int HIN = 256, WIN = 256, C = 3, B = 16;
  constexpr int ROWF  = WIN * C;        // 768 floats per input row
  constexpr int ROWO  = 2 * WIN * C;    // 1536
  constexpr int PLANE = HIN * WIN * C;  // 196608
  constexpr int OPLANE = 512 * 512 * C; // 786432
  constexpr int SEG   = 8;
  constexpr int NI    = SEG + 4;        // 12 row phases
  constexpr int PITCH = 5;              // float4s per slot (16 arrays + pad)
  constexpr int BUFV4 = 272 * PITCH;    // 1360 float4 = 21,760 B used
  constexpr int LDSV4 = 9216;           // 36,864 B total -> 4 blocks/CU limit

  __shared__ float4 lds4[LDSV4];        // padded: occupancy-target control

  const int tid = threadIdx.x;
  const int jj  = blockIdx.x * 256 + tid;  // 0..767 = (t,c)
  const int c   = jj % 3;
  const int t   = jj / 3;
  const int b   = blockIdx.z;

  const int bandStride = B * PLANE;
  const float* a0  = lo2 + (0 * B + b) * PLANE;           // l00
  const float* a1  = lo2 + (1 * B + b) * PLANE;           // l01
  const float* a2  = lo2 + (2 * B + b) * PLANE;           // l10
  const float* a3  = lo2 + (3 * B + b) * PLANE;           // l11
  const float* h00b0 = highs0 + (0 * 3 * B + b) * PLANE;
  const float* h01b0 = highs0 + (1 * 3 * B + b) * PLANE;
  const float* h10b0 = highs0 + (2 * 3 * B + b) * PLANE;
  const float* h11b0 = highs0 + (3 * 3 * B + b) * PLANE;
  const float* h00b1 = h00b0 + bandStride;
  const float* h01b1 = h01b0 + bandStride;
  const float* h10b1 = h10b0 + bandStride;
  const float* h11b1 = h11b0 + bandStride;
  const float* h00b2 = h00b0 + 2*bandStride;
  const float* h01b2 = h01b0 + 2*bandStride;
  const float* h10b2 = h10b0 + 2*bandStride;
  const float* h11b2 = h11b0 + 2*bandStride;

  // staging source offsets (slot k holds global jj' = 256*blockIdx.x - 6 + k)
  int j1 = jj - 6;   if (j1 < 0)     j1 += ROWF;   // slot tid
  int j2 = jj + 250; if (j2 >= ROWF) j2 -= ROWF;   // slot 256+tid (tid<12)
  const bool halo = (tid < 12);

  // circular window, period 6, all indices static after unroll
  float wla0e[6], wla0o[6], wla1e[6], wla1o[6];
  float wha0e[6], wha0o[6], wha1e[6], wha1o[6];
#pragma unroll
  for (int k = 0; k < 6; ++k) {
    wla0e[k]=0.f; wla0o[k]=0.f; wla1e[k]=0.f; wla1o[k]=0.f;
    wha0e[k]=0.f; wha0o[k]=0.f; wha1e[k]=0.f; wha1o[k]=0.f;
  }

  const int s0 = blockIdx.y * SEG;
  float* outb = out + b * OPLANE;

  float4 G0, G1, G2, G3;
  float4 Hh0 = make_float4(0.f,0.f,0.f,0.f), Hh1 = Hh0, Hh2 = Hh0, Hh3 = Hh0;

#define S2_LOAD(I)                                                           \
  {                                                                          \
    const int rb_ = ((s0 - 2 + (I)) & (HIN - 1)) * ROWF;                     \
    const int o1_ = rb_ + j1;                                                \
    G0 = make_float4(a0[o1_], a1[o1_], a2[o1_], a3[o1_]);                    \
    G1 = make_float4(h00b0[o1_], h11b0[o1_], h01b0[o1_], h10b0[o1_]);        \
    G2 = make_float4(h00b1[o1_], h11b1[o1_], h01b1[o1_], h10b1[o1_]);        \
    G3 = make_float4(h00b2[o1_], h11b2[o1_], h01b2[o1_], h10b2[o1_]);        \
    if (halo) {                                                              \
      const int o2_ = rb_ + j2;                                              \
      Hh0 = make_float4(a0[o2_], a1[o2_], a2[o2_], a3[o2_]);                 \
      Hh1 = make_float4(h00b0[o2_], h11b0[o2_], h01b0[o2_], h10b0[o2_]);     \
      Hh2 = make_float4(h00b1[o2_], h11b1[o2_], h01b1[o2_], h10b1[o2_]);     \
      Hh3 = make_float4(h00b2[o2_], h11b2[o2_], h01b2[o2_], h10b2[o2_]);     \
    }                                                                        \
  }

// pre-butterfly + 0.5-fold, then 4x ds_write_b128.
#define S2_WRITE()                                                           \
  {                                                                          \
    float4* w_ = lds4 + tid * PITCH;                                         \
    w_[0] = make_float4(G0.x*0.5f, G0.y*0.5f, G0.z*0.5f, G0.w*0.5f);         \
    w_[1] = make_float4((G1.x+G1.y)*KH, (G1.x-G1.y)*KH,                      \
                        (G1.z+G1.w)*KH, (G1.z-G1.w)*KH);                     \
    w_[2] = make_float4((G2.x+G2.y)*KH, (G2.x-G2.y)*KH,                      \
                        (G2.z+G2.w)*KH, (G2.z-G2.w)*KH);                     \
    w_[3] = make_float4((G3.x+G3.y)*KH, (G3.x-G3.y)*KH,                      \
                        (G3.z+G3.w)*KH, (G3.z-G3.w)*KH);                     \
    if (halo) {                                                              \
      float4* w2_ = lds4 + (256 + tid) * PITCH;                              \
      w2_[0] = make_float4(Hh0.x*0.5f, Hh0.y*0.5f, Hh0.z*0.5f, Hh0.w*0.5f);  \
      w2_[1] = make_float4((Hh1.x+Hh1.y)*KH, (Hh1.x-Hh1.y)*KH,               \
                           (Hh1.z+Hh1.w)*KH, (Hh1.z-Hh1.w)*KH);              \
      w2_[2] = make_float4((Hh2.x+Hh2.y)*KH, (Hh2.x-Hh2.y)*KH,               \
                           (Hh2.z+Hh2.w)*KH, (Hh2.z-Hh2.w)*KH);              \
      w2_[3] = make_float4((Hh3.x+Hh3.y)*KH, (Hh3.x-Hh3.y)*KH,               \
                           (Hh3.z+Hh3.w)*KH, (Hh3.z-Hh3.w)*KH);              \
    }                                                                        \
  }

  // ---- prologue: stage row 0 ----
  S2_LOAD(0);
  S2_WRITE();
  __syncthreads();

#pragma unroll 1
  for (int uo = 0; uo < 2; ++uo) {
#pragma unroll
    for (int k = 0; k < 6; ++k) {
      const int i = uo * 6 + k;           // window slot = k (static; i%6==k)

      if (i < NI - 1) {                   // k<5: always; k==5: uo==0 only
        S2_LOAD(i + 1);
        __builtin_amdgcn_sched_barrier(0);  // keep load issue at phase top
      }

      // ---- column pass from lds4: taps at slot tid + 12 - 3p ----
      float A0e=0.f,A0o=0.f,A1e=0.f,A1o=0.f, H0e=0.f,H0o=0.f,H1e=0.f,H1o=0.f;
#pragma unroll
      for (int p = 0; p < 5; ++p) {
        const float4* qp = lds4 + (tid + (12 - 3*p)) * PITCH;
        const float4 q0 = qp[0], q1 = qp[1], q2 = qp[2], q3 = qp[3];
        const float a0e = c_first[0][9-2*p][0], a0o = c_first[0][8-2*p][0];
        const float b0e = c_first[0][9-2*p][1], b0o = c_first[0][8-2*p][1];
        const float a1e = c_first[1][9-2*p][0], a1o = c_first[1][8-2*p][0];
        const float b1e = c_first[1][9-2*p][1], b1o = c_first[1][8-2*p][1];
        // lo2 terms (q0 = 0.5*(v00,v01,v10,v11))
        A0e += a0e*q0.x + a1e*q0.y;   A0o += a0o*q0.x + a1o*q0.y;
        A1e += a0e*q0.z + a1e*q0.w;   A1o += a0o*q0.z + a1o*q0.w;
        // LH band: q1 = (s1,d1,s2,d2)
        A0e += b0e*q1.x + b1e*q1.z;   A0o += b0o*q1.x + b1o*q1.z;
        A1e += b0e*q1.w + b1e*q1.y;   A1o += b0o*q1.w + b1o*q1.y;
        // HL band
        H0e += a0e*q2.x + a1e*q2.z;   H0o += a0o*q2.x + a1o*q2.z;
        H1e += a0e*q2.w + a1e*q2.y;   H1o += a0o*q2.w + a1o*q2.y;
        // HH band
        H0e += b0e*q3.x + b1e*q3.z;   H0o += b0o*q3.x + b1o*q3.z;
        H1e += b0e*q3.w + b1e*q3.y;   H1o += b0o*q3.w + b1o*q3.y;
      }
      wla0e[k]=A0e; wla0o[k]=A0o; wla1e[k]=A1e; wla1o[k]=A1o;
      wha0e[k]=H0e; wha0o[k]=H0o; wha1e[k]=H1e; wha1o[k]=H1o;

      if (i >= 4) {                       // k>=4: always; k<4: uo>=1
        const int s = s0 + i - 4;
        float o00=0.f, o01=0.f, o10=0.f, o11=0.f;
#pragma unroll
        for (int p = 0; p < 5; ++p) {
          const int kk = (k - p + 6) % 6;   // static
          const float f00 = c_first[0][9-2*p][0], g00 = c_first[0][9-2*p][1];
          const float f01 = c_first[0][8-2*p][0], g01 = c_first[0][8-2*p][1];
          const float f10 = c_first[1][9-2*p][0], g10 = c_first[1][9-2*p][1];
          const float f11 = c_first[1][8-2*p][0], g11 = c_first[1][8-2*p][1];
          o00 += f00*wla0e[kk] + g00*wha0e[kk] + f10*wla1e[kk] + g10*wha1e[kk];
          o01 += f00*wla0o[kk] + g00*wha0o[kk] + f10*wla1o[kk] + g10*wha1o[kk];
          o10 += f01*wla0e[kk] + g01*wha0e[kk] + f11*wla1e[kk] + g11*wha1e[kk];
          o11 += f01*wla0o[kk] + g01*wha0o[kk] + f11*wla1o[kk] + g11*wha1o[kk];
        }
        float* q = outb + (2*s) * ROWO + (2*t) * C + c;
        q[0]        = o00;   // 0.5 folded into staging
        q[C]        = o01;
        q[ROWO]     = o10;
        q[ROWO + C] = o11;
      }

      __syncthreads();                    // B1: all reads of lds4 complete
      if (i < NI - 1) {
        S2_WRITE();                       // overwrite with row i+1
      }
      __syncthreads();                    // B2: writes visible
    }
  }
#undef S2_LOAD
#undef S2_WRITE
}

extern "C" void kernel_launch(void* const* d_in, const int* in_sizes, int n_in,
                              void* d_out, int out_size, void* d_ws, size_t ws_size,
                              hipStream_t stream) {
  const float* highs0 = (const float*)d_in[0];  // (2,2,3,16,256,256,3)
  const float* highs1 = (const float*)d_in[1];  // (2,2,3,16,128,128,3)
  const float* lows   = (const float*)d_in[2];  // (2,2,16,128,128,3)
  float* out = (float*)d_out;                   // (16,512,512,3)
  float* lo2 = (float*)d_ws;                    // 50.3 MB

  // Stage 1 (R9 form): 8 row segments of 16; 4x16 planes
  dim3 b1(128), g1(3, 8, 64);
  hipLaunchKernelGGL(idtcwt_stage1, g1, b1, 0, stream, lows, highs1, lo2);

  // Stage 2: 32 row segments of 8; 16 batches -> 1536 blocks
  dim3 b2(256), g2(3, 32, 16);
  hipLaunchKernelGGL(idtcwt_stage2, g2, b2, 0, stream, lo2, highs0, out);
}

// Round 13
// 119.763 us; speedup vs baseline: 3.1756x; 1.2499x over previous
//
#include <hip/hip_runtime.h>

#define INV_SQRT2 0.70710678118654752440f
#define KH 0.35355339059327376220f   // INV_SQRT2 * 0.5 (output scale folded in)

// Stage-2 (first-stage) filter table as constexpr: compile-time indices after
// unroll -> coefficients fold to immediates; structural zeros kill 20% of FMAs.
constexpr float c_first[2][10][2] = {
  { { 0.00000000000000f,  0.00000000000000f},
    {-0.08838834764832f, -0.01122679215254f},
    { 0.08838834764832f,  0.01122679215254f},
    { 0.69587998903400f,  0.08838834764832f},
    { 0.69587998903400f,  0.08838834764832f},
    { 0.08838834764832f, -0.69587998903400f},
    {-0.08838834764832f,  0.69587998903400f},
    { 0.01122679215254f, -0.08838834764832f},
    { 0.01122679215254f, -0.08838834764832f},
    { 0.00000000000000f,  0.00000000000000f} },
  { { 0.01122679215254f,  0.00000000000000f},
    { 0.01122679215254f,  0.00000000000000f},
    {-0.08838834764832f, -0.08838834764832f},
    { 0.08838834764832f, -0.08838834764832f},
    { 0.69587998903400f,  0.69587998903400f},
    { 0.69587998903400f, -0.69587998903400f},
    { 0.08838834764832f,  0.08838834764832f},
    {-0.08838834764832f,  0.08838834764832f},
    { 0.00000000000000f,  0.01122679215254f},
    { 0.00000000000000f, -0.01122679215254f} }
};

// Stage-1 table stays __constant__: its [n]/[m] indices are runtime-uniform.
__constant__ float c_qshift[2][10][2] = {
  { { 0.03516384f,  0.00000000f},
    { 0.00000000f,  0.00000000f},
    {-0.08832942f, -0.11430184f},
    { 0.23389032f,  0.00000000f},
    { 0.76027237f,  0.58751830f},
    { 0.58751830f, -0.76027237f},
    { 0.00000000f,  0.23389032f},
    {-0.11430184f,  0.08832942f},
    { 0.00000000f,  0.00000000f},
    { 0.00000000f, -0.03516384f} },
  { { 0.00000000f, -0.03516384f},
    { 0.00000000f,  0.00000000f},
    {-0.11430184f,  0.08832942f},
    { 0.00000000f,  0.23389032f},
    { 0.58751830f, -0.76027237f},
    { 0.76027237f,  0.58751830f},
    { 0.23389032f,  0.00000000f},
    {-0.08832942f, -0.11430184f},
    { 0.00000000f,  0.00000000f},
    { 0.03516384f,  0.00000000f} }
};

// ---------------------------------------------------------------------------
// Stage 1: level-2 synthesis (Q-shift) — R9 exact form (proven ~23us):
// SEG=16, launch_bounds(128,3), gather + keep-alive pins.
// ---------------------------------------------------------------------------
__global__ __launch_bounds__(128, 3) void idtcwt_stage1(
    const float* __restrict__ lows, const float* __restrict__ highs1,
    float* __restrict__ lo2)
{
  constexpr int HIN = 128, WIN = 128, C = 3, B = 16;
  constexpr int ROWF  = WIN * C;        // 384 floats per input row
  constexpr int ROWO  = 2 * WIN * C;    // 768 floats per output row
  constexpr int PLANE = HIN * WIN * C;  // 49152
  constexpr int SEG   = 16;

  const int jj = blockIdx.x * 128 + threadIdx.x;  // 0..383 = (t, c)
  const int c  = jj % 3;
  const int t  = jj / 3;                // input column 0..127
  const int z  = blockIdx.z;            // combo*16 + b
  const int combo = z >> 4;
  const int b     = z & 15;
  const int m = combo >> 1, n = combo & 1;

  const float* lo = lows + (combo * B + b) * PLANE;
  const int pa = (m == n) ? 0 : 1;
  const int pb = (m == n) ? 3 : 2;
  const float sgn = (m == 0) ? 1.0f : -1.0f;
  const int bandStride = B * PLANE;     // 786432
  const float* hA = highs1 + (pa * 3 * B + b) * PLANE;
  const float* hB = highs1 + (pb * 3 * B + b) * PLANE;

  int wc3[5];
#pragma unroll
  for (int p = 0; p < 5; ++p) {
    int w = t + 2 - p;
    if (w >= WIN) w -= WIN;
    if (w < 0)  w += WIN;
    wc3[p] = w * C + c;
  }

  float lae[5], lao[5], hae[5], hao[5];
#pragma unroll
  for (int k = 0; k < 5; ++k) { lae[k]=0.f; lao[k]=0.f; hae[k]=0.f; hao[k]=0.f; }

  const int s0 = blockIdx.y * SEG;
  float* outp = lo2 + (combo * B + b) * (4 * PLANE);

#pragma unroll 1
  for (int ui = 0; ui < SEG + 4; ++ui) {
    const int u  = (s0 - 2 + ui) & (HIN - 1);
#pragma unroll
    for (int k = 0; k < 4; ++k) { lae[k]=lae[k+1]; lao[k]=lao[k+1]; hae[k]=hae[k+1]; hao[k]=hao[k+1]; }
    const int rb = u * ROWF;

    float rl[5], rA[3][5], rB[3][5];
#pragma unroll
    for (int p = 0; p < 5; ++p) {
      const int idx = rb + wc3[p];
      rl[p]    = lo[idx];
      rA[0][p] = hA[idx];
      rB[0][p] = hB[idx];
      rA[1][p] = hA[idx +   bandStride];
      rB[1][p] = hB[idx +   bandStride];
      rA[2][p] = hA[idx + 2*bandStride];
      rB[2][p] = hB[idx + 2*bandStride];
    }
    // keep-alive pins: forbid chunking of the 35-load batch
    asm volatile("" :: "v"(rl[0]),"v"(rl[1]),"v"(rl[2]),"v"(rl[3]),"v"(rl[4]),
                       "v"(rA[0][0]),"v"(rA[0][1]),"v"(rA[0][2]),"v"(rA[0][3]),"v"(rA[0][4]),
                       "v"(rA[1][0]),"v"(rA[1][1]),"v"(rA[1][2]),"v"(rA[1][3]),"v"(rA[1][4]));
    asm volatile("" :: "v"(rA[2][0]),"v"(rA[2][1]),"v"(rA[2][2]),"v"(rA[2][3]),"v"(rA[2][4]),
                       "v"(rB[0][0]),"v"(rB[0][1]),"v"(rB[0][2]),"v"(rB[0][3]),"v"(rB[0][4]),
                       "v"(rB[1][0]),"v"(rB[1][1]),"v"(rB[1][2]),"v"(rB[1][3]),"v"(rB[1][4]));
    asm volatile("" :: "v"(rB[2][0]),"v"(rB[2][1]),"v"(rB[2][2]),"v"(rB[2][3]),"v"(rB[2][4]));

    float aLe=0.f, aLo=0.f, aHe=0.f, aHo=0.f;
#pragma unroll
    for (int p = 0; p < 5; ++p) {
      const float lv  = rl[p];
      const float lhv = (rA[0][p] + sgn * rB[0][p]) * INV_SQRT2;
      const float hlv = (rA[1][p] + sgn * rB[1][p]) * INV_SQRT2;
      const float hhv = (rA[2][p] + sgn * rB[2][p]) * INV_SQRT2;
      const float ce0 = c_qshift[n][9 - 2*p][0], ce1 = c_qshift[n][9 - 2*p][1];
      const float co0 = c_qshift[n][8 - 2*p][0], co1 = c_qshift[n][8 - 2*p][1];
      aLe += ce0 * lv  + ce1 * lhv;
      aLo += co0 * lv  + co1 * lhv;
      aHe += ce0 * hlv + ce1 * hhv;
      aHo += co0 * hlv + co1 * hhv;
    }
    lae[4]=aLe; lao[4]=aLo; hae[4]=aHe; hao[4]=aHo;

    if (ui >= 4) {
      const int s = s0 + ui - 4;
      float o00=0.f, o01=0.f, o10=0.f, o11=0.f;
#pragma unroll
      for (int p = 0; p < 5; ++p) {
        const float f0l = c_qshift[m][9 - 2*p][0], f0h = c_qshift[m][9 - 2*p][1];
        const float f1l = c_qshift[m][8 - 2*p][0], f1h = c_qshift[m][8 - 2*p][1];
        o00 += f0l*lae[4-p] + f0h*hae[4-p];
        o01 += f0l*lao[4-p] + f0h*hao[4-p];
        o10 += f1l*lae[4-p] + f1h*hae[4-p];
        o11 += f1l*lao[4-p] + f1h*hao[4-p];
      }
      float* q = outp + (2*s) * ROWO + (2*t) * C + c;
      q[0]        = o00;
      q[C]        = o01;
      q[ROWO]     = o10;
      q[ROWO + C] = o11;
    }
  }
}

// ---------------------------------------------------------------------------
// Stage 2: single-buffer SEG=8 + split barriers (R12 structure). R12's LDS
// units bug (147,456 B -> 1 block/CU, budget 512) accidentally PROVED the
// mechanism: the barrier fence blocks load-sinking, so with a big enough
// VGPR budget the compiler holds the whole prefetch batch live (VGPR=132,
// no spill) -> per-wave throughput 2x R9's. 126us at just 4 waves/CU.
// R13: pad LDS to 49,152 B exactly -> 3 blocks/CU -> budget 512/3=170 >= 132
// -> same high-MLP code with 12 waves/CU (3x resident blocks).
// ---------------------------------------------------------------------------
__global__ __launch_bounds__(256, 4) void idtcwt_stage2(
    const float* __restrict__ lo2, const float* __restrict__ highs0,
    float* __restrict__ out)
{
  constexpr int HIN = 256, WIN = 256, C = 3, B = 16;
  constexpr int ROWF  = WIN * C;        // 768 floats per input row
  constexpr int ROWO  = 2 * WIN * C;    // 1536
  constexpr int PLANE = HIN * WIN * C;  // 196608
  constexpr int OPLANE = 512 * 512 * C; // 786432
  constexpr int SEG   = 8;
  constexpr int NI    = SEG + 4;        // 12 row phases
  constexpr int PITCH = 5;              // float4s per slot (16 arrays + pad)
  constexpr int BUFV4 = 272 * PITCH;    // 1360 float4 = 21,760 B used
  constexpr int LDSV4 = 3072;           // 3072 float4 = 49,152 B -> 3 blk/CU

  __shared__ float4 lds4[LDSV4];        // padded: occupancy/VGPR-budget control

  const int tid = threadIdx.x;
  const int jj  = blockIdx.x * 256 + tid;  // 0..767 = (t,c)
  const int c   = jj % 3;
  const int t   = jj / 3;
  const int b   = blockIdx.z;

  const int bandStride = B * PLANE;
  const float* a0  = lo2 + (0 * B + b) * PLANE;           // l00
  const float* a1  = lo2 + (1 * B + b) * PLANE;           // l01
  const float* a2  = lo2 + (2 * B + b) * PLANE;           // l10
  const float* a3  = lo2 + (3 * B + b) * PLANE;           // l11
  const float* h00b0 = highs0 + (0 * 3 * B + b) * PLANE;
  const float* h01b0 = highs0 + (1 * 3 * B + b) * PLANE;
  const float* h10b0 = highs0 + (2 * 3 * B + b) * PLANE;
  const float* h11b0 = highs0 + (3 * 3 * B + b) * PLANE;
  const float* h00b1 = h00b0 + bandStride;
  const float* h01b1 = h01b0 + bandStride;
  const float* h10b1 = h10b0 + bandStride;
  const float* h11b1 = h11b0 + bandStride;
  const float* h00b2 = h00b0 + 2*bandStride;
  const float* h01b2 = h01b0 + 2*bandStride;
  const float* h10b2 = h10b0 + 2*bandStride;
  const float* h11b2 = h11b0 + 2*bandStride;

  // staging source offsets (slot k holds global jj' = 256*blockIdx.x - 6 + k)
  int j1 = jj - 6;   if (j1 < 0)     j1 += ROWF;   // slot tid
  int j2 = jj + 250; if (j2 >= ROWF) j2 -= ROWF;   // slot 256+tid (tid<12)
  const bool halo = (tid < 12);

  // circular window, period 6, all indices static after unroll
  float wla0e[6], wla0o[6], wla1e[6], wla1o[6];
  float wha0e[6], wha0o[6], wha1e[6], wha1o[6];
#pragma unroll
  for (int k = 0; k < 6; ++k) {
    wla0e[k]=0.f; wla0o[k]=0.f; wla1e[k]=0.f; wla1o[k]=0.f;
    wha0e[k]=0.f; wha0o[k]=0.f; wha1e[k]=0.f; wha1o[k]=0.f;
  }

  const int s0 = blockIdx.y * SEG;
  float* outb = out + b * OPLANE;

  float4 G0, G1, G2, G3;
  float4 Hh0 = make_float4(0.f,0.f,0.f,0.f), Hh1 = Hh0, Hh2 = Hh0, Hh3 = Hh0;

#define S2_LOAD(I)                                                           \
  {                                                                          \
    const int rb_ = ((s0 - 2 + (I)) & (HIN - 1)) * ROWF;                     \
    const int o1_ = rb_ + j1;                                                \
    G0 = make_float4(a0[o1_], a1[o1_], a2[o1_], a3[o1_]);                    \
    G1 = make_float4(h00b0[o1_], h11b0[o1_], h01b0[o1_], h10b0[o1_]);        \
    G2 = make_float4(h00b1[o1_], h11b1[o1_], h01b1[o1_], h10b1[o1_]);        \
    G3 = make_float4(h00b2[o1_], h11b2[o1_], h01b2[o1_], h10b2[o1_]);        \
    if (halo) {                                                              \
      const int o2_ = rb_ + j2;                                              \
      Hh0 = make_float4(a0[o2_], a1[o2_], a2[o2_], a3[o2_]);                 \
      Hh1 = make_float4(h00b0[o2_], h11b0[o2_], h01b0[o2_], h10b0[o2_]);     \
      Hh2 = make_float4(h00b1[o2_], h11b1[o2_], h01b1[o2_], h10b1[o2_]);     \
      Hh3 = make_float4(h00b2[o2_], h11b2[o2_], h01b2[o2_], h10b2[o2_]);     \
    }                                                                        \
  }

// pre-butterfly + 0.5-fold, then 4x ds_write_b128.
#define S2_WRITE()                                                           \
  {                                                                          \
    float4* w_ = lds4 + tid * PITCH;                                         \
    w_[0] = make_float4(G0.x*0.5f, G0.y*0.5f, G0.z*0.5f, G0.w*0.5f);         \
    w_[1] = make_float4((G1.x+G1.y)*KH, (G1.x-G1.y)*KH,                      \
                        (G1.z+G1.w)*KH, (G1.z-G1.w)*KH);                     \
    w_[2] = make_float4((G2.x+G2.y)*KH, (G2.x-G2.y)*KH,                      \
                        (G2.z+G2.w)*KH, (G2.z-G2.w)*KH);                     \
    w_[3] = make_float4((G3.x+G3.y)*KH, (G3.x-G3.y)*KH,                      \
                        (G3.z+G3.w)*KH, (G3.z-G3.w)*KH);                     \
    if (halo) {                                                              \
      float4* w2_ = lds4 + (256 + tid) * PITCH;                              \
      w2_[0] = make_float4(Hh0.x*0.5f, Hh0.y*0.5f, Hh0.z*0.5f, Hh0.w*0.5f);  \
      w2_[1] = make_float4((Hh1.x+Hh1.y)*KH, (Hh1.x-Hh1.y)*KH,               \
                           (Hh1.z+Hh1.w)*KH, (Hh1.z-Hh1.w)*KH);              \
      w2_[2] = make_float4((Hh2.x+Hh2.y)*KH, (Hh2.x-Hh2.y)*KH,               \
                           (Hh2.z+Hh2.w)*KH, (Hh2.z-Hh2.w)*KH);              \
      w2_[3] = make_float4((Hh3.x+Hh3.y)*KH, (Hh3.x-Hh3.y)*KH,               \
                           (Hh3.z+Hh3.w)*KH, (Hh3.z-Hh3.w)*KH);              \
    }                                                                        \
  }

  // ---- prologue: stage row 0 ----
  S2_LOAD(0);
  S2_WRITE();
  __syncthreads();

#pragma unroll 1
  for (int uo = 0; uo < 2; ++uo) {
#pragma unroll
    for (int k = 0; k < 6; ++k) {
      const int i = uo * 6 + k;           // window slot = k (static; i%6==k)

      if (i < NI - 1) {                   // k<5: always; k==5: uo==0 only
        S2_LOAD(i + 1);
        __builtin_amdgcn_sched_barrier(0);  // keep load issue at phase top
      }

      // ---- column pass from lds4: taps at slot tid + 12 - 3p ----
      float A0e=0.f,A0o=0.f,A1e=0.f,A1o=0.f, H0e=0.f,H0o=0.f,H1e=0.f,H1o=0.f;
#pragma unroll
      for (int p = 0; p < 5; ++p) {
        const float4* qp = lds4 + (tid + (12 - 3*p)) * PITCH;
        const float4 q0 = qp[0], q1 = qp[1], q2 = qp[2], q3 = qp[3];
        const float a0e = c_first[0][9-2*p][0], a0o = c_first[0][8-2*p][0];
        const float b0e = c_first[0][9-2*p][1], b0o = c_first[0][8-2*p][1];
        const float a1e = c_first[1][9-2*p][0], a1o = c_first[1][8-2*p][0];
        const float b1e = c_first[1][9-2*p][1], b1o = c_first[1][8-2*p][1];
        // lo2 terms (q0 = 0.5*(v00,v01,v10,v11))
        A0e += a0e*q0.x + a1e*q0.y;   A0o += a0o*q0.x + a1o*q0.y;
        A1e += a0e*q0.z + a1e*q0.w;   A1o += a0o*q0.z + a1o*q0.w;
        // LH band: q1 = (s1,d1,s2,d2)
        A0e += b0e*q1.x + b1e*q1.z;   A0o += b0o*q1.x + b1o*q1.z;
        A1e += b0e*q1.w + b1e*q1.y;   A1o += b0o*q1.w + b1o*q1.y;
        // HL band
        H0e += a0e*q2.x + a1e*q2.z;   H0o += a0o*q2.x + a1o*q2.z;
        H1e += a0e*q2.w + a1e*q2.y;   H1o += a0o*q2.w + a1o*q2.y;
        // HH band
        H0e += b0e*q3.x + b1e*q3.z;   H0o += b0o*q3.x + b1o*q3.z;
        H1e += b0e*q3.w + b1e*q3.y;   H1o += b0o*q3.w + b1o*q3.y;
      }
      wla0e[k]=A0e; wla0o[k]=A0o; wla1e[k]=A1e; wla1o[k]=A1o;
      wha0e[k]=H0e; wha0o[k]=H0o; wha1e[k]=H1e; wha1o[k]=H1o;

      if (i >= 4) {                       // k>=4: always; k<4: uo>=1
        const int s = s0 + i - 4;
        float o00=0.f, o01=0.f, o10=0.f, o11=0.f;
#pragma unroll
        for (int p = 0; p < 5; ++p) {
          const int kk = (k - p + 6) % 6;   // static
          const float f00 = c_first[0][9-2*p][0], g00 = c_first[0][9-2*p][1];
          const float f01 = c_first[0][8-2*p][0], g01 = c_first[0][8-2*p][1];
          const float f10 = c_first[1][9-2*p][0], g10 = c_first[1][9-2*p][1];
          const float f11 = c_first[1][8-2*p][0], g11 = c_first[1][8-2*p][1];
          o00 += f00*wla0e[kk] + g00*wha0e[kk] + f10*wla1e[kk] + g10*wha1e[kk];
          o01 += f00*wla0o[kk] + g00*wha0o[kk] + f10*wla1o[kk] + g10*wha1o[kk];
          o10 += f01*wla0e[kk] + g01*wha0e[kk] + f11*wla1e[kk] + g11*wha1e[kk];
          o11 += f01*wla0o[kk] + g01*wha0o[kk] + f11*wla1o[kk] + g11*wha1o[kk];
        }
        float* q = outb + (2*s) * ROWO + (2*t) * C + c;
        q[0]        = o00;   // 0.5 folded into staging
        q[C]        = o01;
        q[ROWO]     = o10;
        q[ROWO + C] = o11;
      }

      __syncthreads();                    // B1: all reads of lds4 complete
      if (i < NI - 1) {
        S2_WRITE();                       // overwrite with row i+1
      }
      __syncthreads();                    // B2: writes visible
    }
  }
#undef S2_LOAD
#undef S2_WRITE
}

extern "C" void kernel_launch(void* const* d_in, const int* in_sizes, int n_in,
                              void* d_out, int out_size, void* d_ws, size_t ws_size,
                              hipStream_t stream) {
  const float* highs0 = (const float*)d_in[0];  // (2,2,3,16,256,256,3)
  const float* highs1 = (const float*)d_in[1];  // (2,2,3,16,128,128,3)
  const float* lows   = (const float*)d_in[2];  // (2,2,16,128,128,3)
  float* out = (float*)d_out;                   // (16,512,512,3)
  float* lo2 = (float*)d_ws;                    // 50.3 MB

  // Stage 1 (R9 form): 8 row segments of 16; 4x16 planes
  dim3 b1(128), g1(3, 8, 64);
  hipLaunchKernelGGL(idtcwt_stage1, g1, b1, 0, stream, lows, highs1, lo2);

  // Stage 2: 32 row segments of 8; 16 batches -> 1536 blocks
  dim3 b2(256), g2(3, 32, 16);
  hipLaunchKernelGGL(idtcwt_stage2, g2, b2, 0, stream, lo2, highs0, out);
}